// Round 3
// baseline (418.154 us; speedup 1.0000x reference)
//
#include <hip/hip_runtime.h>

// Problem constants (HyperGCNConv: N=100000, M=50000, K=8, DIN=DOUT=128)
#define NV 100000
#define ME 50000
#define NINC (ME * 8)                     // 400000 incidences
#define NBLK ((NV + 255) / 256)           // 391 scan blocks
constexpr float WMED = 1.0f / 13.0f;      // 1/(2K-3), K=8

// ---------------- K1: Y = X @ W + b (fp32, vector ALU) ----------------
// Register-blocked: block 256 threads, tile 128 rows x 128 cols. (R2 version)
__global__ __launch_bounds__(256) void k_gemm(const float* __restrict__ X,
                                              const float* __restrict__ W,
                                              const float* __restrict__ bias,
                                              float* __restrict__ Y) {
    __shared__ float sX[128 * 68];   // [row][k] , k-half, stride 68
    __shared__ float sW[64 * 128];   // [k][col]
    const int t = threadIdx.x;
    const int cg = t & 31;
    const int rg = t >> 5;
    const int row0 = blockIdx.x * 128;

    float acc[16][4];
    #pragma unroll
    for (int i = 0; i < 16; ++i) {
        acc[i][0] = 0.f; acc[i][1] = 0.f; acc[i][2] = 0.f; acc[i][3] = 0.f;
    }

    for (int h = 0; h < 2; ++h) {
        __syncthreads();
        #pragma unroll
        for (int i = 0; i < 8; ++i) {
            const int idx = t + i * 256;
            const int row = idx >> 4;
            const int kq  = idx & 15;
            int gr = row0 + row; if (gr > NV - 1) gr = NV - 1;
            const float4 v = *(const float4*)(X + (long)gr * 128 + h * 64 + kq * 4);
            *(float4*)(sX + row * 68 + kq * 4) = v;
        }
        #pragma unroll
        for (int i = 0; i < 8; ++i) {
            const int idx = t + i * 256;
            const int k  = idx >> 5;
            const int cq = idx & 31;
            const float4 v = *(const float4*)(W + (long)(h * 64 + k) * 128 + cq * 4);
            *(float4*)(sW + k * 128 + cq * 4) = v;
        }
        __syncthreads();

        #pragma unroll 4
        for (int k4 = 0; k4 < 16; ++k4) {
            const float4 w0 = *(const float4*)(sW + (k4 * 4 + 0) * 128 + cg * 4);
            const float4 w1 = *(const float4*)(sW + (k4 * 4 + 1) * 128 + cg * 4);
            const float4 w2 = *(const float4*)(sW + (k4 * 4 + 2) * 128 + cg * 4);
            const float4 w3 = *(const float4*)(sW + (k4 * 4 + 3) * 128 + cg * 4);
            #pragma unroll
            for (int i = 0; i < 16; ++i) {
                const float4 xq = *(const float4*)(sX + (rg * 16 + i) * 68 + k4 * 4);
                acc[i][0] = fmaf(xq.x, w0.x, acc[i][0]);
                acc[i][1] = fmaf(xq.x, w0.y, acc[i][1]);
                acc[i][2] = fmaf(xq.x, w0.z, acc[i][2]);
                acc[i][3] = fmaf(xq.x, w0.w, acc[i][3]);
                acc[i][0] = fmaf(xq.y, w1.x, acc[i][0]);
                acc[i][1] = fmaf(xq.y, w1.y, acc[i][1]);
                acc[i][2] = fmaf(xq.y, w1.z, acc[i][2]);
                acc[i][3] = fmaf(xq.y, w1.w, acc[i][3]);
                acc[i][0] = fmaf(xq.z, w2.x, acc[i][0]);
                acc[i][1] = fmaf(xq.z, w2.y, acc[i][1]);
                acc[i][2] = fmaf(xq.z, w2.z, acc[i][2]);
                acc[i][3] = fmaf(xq.z, w2.w, acc[i][3]);
                acc[i][0] = fmaf(xq.w, w3.x, acc[i][0]);
                acc[i][1] = fmaf(xq.w, w3.y, acc[i][1]);
                acc[i][2] = fmaf(xq.w, w3.z, acc[i][2]);
                acc[i][3] = fmaf(xq.w, w3.w, acc[i][3]);
            }
        }
    }

    const float4 bj = *(const float4*)(bias + cg * 4);
    #pragma unroll
    for (int i = 0; i < 16; ++i) {
        const int gr = row0 + rg * 16 + i;
        if (gr < NV) {
            float4 o;
            o.x = acc[i][0] + bj.x; o.y = acc[i][1] + bj.y;
            o.z = acc[i][2] + bj.z; o.w = acc[i][3] + bj.w;
            *(float4*)(Y + (long)gr * 128 + cg * 4) = o;
        }
    }
}

// ---------------- K2a: init deg=1, cnt=0, rowptr[NV]=NINC ----------------
__global__ __launch_bounds__(256) void k_init(float* __restrict__ deg,
                                              int* __restrict__ cnt,
                                              int* __restrict__ rowptr) {
    const int i = blockIdx.x * 256 + threadIdx.x;
    if (i < NV) { deg[i] = 1.0f; cnt[i] = 0; }
    if (i == 0) rowptr[NV] = NINC;
}

// ---------------- CSR build: histogram ----------------
__global__ __launch_bounds__(256) void k_hist(const int* __restrict__ vertex,
                                              int* __restrict__ cnt) {
    const int j = blockIdx.x * 256 + threadIdx.x;
    if (j < NINC) atomicAdd(cnt + vertex[j], 1);
}

// ---------------- CSR build: scan stage 1 (per-block sums) ----------------
__global__ __launch_bounds__(256) void k_scan1(const int* __restrict__ cnt,
                                               int* __restrict__ bsum) {
    __shared__ int s[256];
    const int t = threadIdx.x;
    const int i = blockIdx.x * 256 + t;
    s[t] = (i < NV) ? cnt[i] : 0;
    __syncthreads();
    #pragma unroll
    for (int off = 128; off >= 1; off >>= 1) {
        if (t < off) s[t] += s[t + off];
        __syncthreads();
    }
    if (t == 0) bsum[blockIdx.x] = s[0];
}

// ---------------- CSR build: scan stage 2 (exclusive scan of block sums) ---
__global__ __launch_bounds__(64) void k_scan2(const int* __restrict__ bsum,
                                              int* __restrict__ boff) {
    const int lane = threadIdx.x;   // single wave
    int running = 0;
    for (int c = 0; c * 64 < NBLK; ++c) {
        const int idx = c * 64 + lane;
        int v = (idx < NBLK) ? bsum[idx] : 0;
        int x = v;
        #pragma unroll
        for (int off = 1; off < 64; off <<= 1) {
            const int n = __shfl_up(x, off);
            if (lane >= off) x += n;
        }
        if (idx < NBLK) boff[idx] = running + x - v;   // exclusive
        running += __shfl(x, 63);
    }
}

// ---------------- CSR build: scan stage 3 (rowptr + fill ptr) ----------------
__global__ __launch_bounds__(256) void k_scan3(const int* __restrict__ cnt,
                                               const int* __restrict__ boff,
                                               int* __restrict__ rowptr,
                                               int* __restrict__ fill) {
    __shared__ int s[256];
    const int t = threadIdx.x;
    const int i = blockIdx.x * 256 + t;
    const int v = (i < NV) ? cnt[i] : 0;
    s[t] = v;
    __syncthreads();
    #pragma unroll
    for (int off = 1; off < 256; off <<= 1) {
        const int add = (t >= off) ? s[t - off] : 0;
        __syncthreads();
        s[t] += add;
        __syncthreads();
    }
    if (i < NV) {
        const int excl = boff[blockIdx.x] + s[t] - v;
        rowptr[i] = excl;
        fill[i] = excl;
    }
}

// ---------------- CSR build: fill entries ----------------
__global__ __launch_bounds__(256) void k_fill(const int* __restrict__ vertex,
                                              int* __restrict__ fill,
                                              int* __restrict__ entries) {
    const int j = blockIdx.x * 256 + threadIdx.x;
    if (j < NINC) {
        const int v = vertex[j];
        const int slot = atomicAdd(fill + v, 1);
        entries[slot] = j;
    }
}

// ---------------- K2: per-hyperedge argmax pair + deg atomics ----------------
__global__ __launch_bounds__(256) void k_edge(const float* __restrict__ Y,
                                              const int* __restrict__ vertex,
                                              float* __restrict__ deg,
                                              int* __restrict__ uvpos) {
    __shared__ float sF[4][8 * 132];
    const int wid = threadIdx.x >> 6;
    const int lane = threadIdx.x & 63;
    const int m = blockIdx.x * 4 + wid;
    float* F = sF[wid];

    int verts[8];
    #pragma unroll
    for (int p = 0; p < 8; ++p) verts[p] = vertex[m * 8 + p];

    #pragma unroll
    for (int p = 0; p < 8; ++p) {
        const float2 v = *(const float2*)(Y + (long)verts[p] * 128 + lane * 2);
        *(float2*)(F + p * 132 + lane * 2) = v;
    }
    __syncthreads();

    const int k = lane >> 3, l = lane & 7;
    float acc = 0.0f;
    const float4* ra = (const float4*)(F + k * 132);
    const float4* rb = (const float4*)(F + l * 132);
    #pragma unroll
    for (int d4 = 0; d4 < 32; ++d4) {
        const float4 a = ra[d4], b = rb[d4];
        acc = fmaf(a.x, b.x, acc);
        acc = fmaf(a.y, b.y, acc);
        acc = fmaf(a.z, b.z, acc);
        acc = fmaf(a.w, b.w, acc);
    }
    const float sqk = __shfl(acc, k * 9);
    const float sql = __shfl(acc, l * 9);
    float v = sqk + sql - 2.0f * acc;
    int idx = lane;
    #pragma unroll
    for (int off = 32; off >= 1; off >>= 1) {
        const float ov = __shfl_xor(v, off);
        const int oi = __shfl_xor(idx, off);
        if (ov > v || (ov == v && oi < idx)) { v = ov; idx = oi; }
    }
    const int ui = idx >> 3, vi = idx & 7;
    if (lane == 0) uvpos[m] = idx;

    float summed = 0.0f;
    #pragma unroll
    for (int p = 0; p < 8; ++p) summed += (p != ui && p != vi) ? WMED : 0.0f;
    if (lane < 8) {
        const int p = lane;
        if (p != ui && p != vi) atomicAdd(deg + verts[p], 2.0f * WMED);
    } else if (lane == 8) {
        atomicAdd(deg + verts[ui], WMED + summed);
    } else if (lane == 9) {
        atomicAdd(deg + verts[vi], WMED + summed);
    }
}

// ---------------- K3: dinv = rsqrt(deg); Xs = Y*dinv (in place) ----------------
__global__ __launch_bounds__(256) void k_xs(float* __restrict__ Y,
                                            const float* __restrict__ deg,
                                            float* __restrict__ dinv) {
    const long t = (long)blockIdx.x * 256 + threadIdx.x;   // over N*32 float4s
    const int i = (int)(t >> 5);
    const float di = rsqrtf(deg[i]);
    if ((t & 31) == 0) dinv[i] = di;
    float4 y = ((const float4*)Y)[t];
    y.x *= di; y.y *= di; y.z *= di; y.w *= di;
    ((float4*)Y)[t] = y;
}

// ---------------- K4: per-vertex gather + relu(dinv*...) ----------------
// one wave per vertex; lane handles dims (lane, lane+64). No atomics.
__global__ __launch_bounds__(256) void k_gather(const float* __restrict__ Xs,
                                                const int* __restrict__ vertex,
                                                const int* __restrict__ uvpos,
                                                const int* __restrict__ rowptr,
                                                const int* __restrict__ entries,
                                                const float* __restrict__ dinv,
                                                float* __restrict__ out) {
    const int wid = threadIdx.x >> 6;
    const int lane = threadIdx.x & 63;
    const int i = blockIdx.x * 4 + wid;           // vertex id
    const int d0 = lane, d1 = lane + 64;

    float acc0 = Xs[(long)i * 128 + d0];          // self-loop term (Xs[i])
    float acc1 = Xs[(long)i * 128 + d1];

    const int start = rowptr[i];
    const int end   = rowptr[i + 1];
    for (int e = start; e < end; ++e) {
        const int j = entries[e];
        const int m = j >> 3;
        const int p = j & 7;
        const int idx = uvpos[m];
        const int ui = idx >> 3, vi = idx & 7;
        const int* vm = vertex + m * 8;
        if (p == ui || p == vi) {
            // role u (or v): w*Xs[other] + w*sum_{mediators} Xs[med]
            const int other = (p == ui) ? vm[vi] : vm[ui];
            float s0 = Xs[(long)other * 128 + d0];
            float s1 = Xs[(long)other * 128 + d1];
            #pragma unroll
            for (int p2 = 0; p2 < 8; ++p2) {
                if (p2 != ui && p2 != vi) {
                    const float* row = Xs + (long)vm[p2] * 128;
                    s0 += row[d0];
                    s1 += row[d1];
                }
            }
            acc0 = fmaf(WMED, s0, acc0);
            acc1 = fmaf(WMED, s1, acc1);
        } else {
            // mediator role: w*(Xs[u] + Xs[v])
            const float* ru = Xs + (long)vm[ui] * 128;
            const float* rv = Xs + (long)vm[vi] * 128;
            acc0 = fmaf(WMED, ru[d0] + rv[d0], acc0);
            acc1 = fmaf(WMED, ru[d1] + rv[d1], acc1);
        }
    }

    const float di = dinv[i];
    out[(long)i * 128 + d0] = fmaxf(acc0 * di, 0.0f);
    out[(long)i * 128 + d1] = fmaxf(acc1 * di, 0.0f);
}

extern "C" void kernel_launch(void* const* d_in, const int* in_sizes, int n_in,
                              void* d_out, int out_size, void* d_ws, size_t ws_size,
                              hipStream_t stream) {
    const float* X      = (const float*)d_in[0];   // [N,128]
    const int*   vertex = (const int*)d_in[1];     // [M*8]
    // d_in[2] = edges (repeat(arange(M),8)) -- unused
    const float* W      = (const float*)d_in[3];   // [128,128]
    const float* bias   = (const float*)d_in[4];   // [128]
    float* out = (float*)d_out;                    // [N,128]

    // workspace: Y/Xs[N*128] | deg[N] | dinv[N] | uvpos[M] | cnt[N] |
    //            rowptr[N+1] | fill[N] | bsum[NBLK] | boff[NBLK] | entries[NINC]
    float* Y      = (float*)d_ws;
    float* deg    = Y + (long)NV * 128;
    float* dinv   = deg + NV;
    int*   uvpos  = (int*)(dinv + NV);
    int*   cnt    = uvpos + ME;
    int*   rowptr = cnt + NV;
    int*   fill   = rowptr + NV + 1;
    int*   bsum   = fill + NV;
    int*   boff   = bsum + NBLK;
    int*   entries = boff + NBLK;

    k_gemm <<<(NV + 127) / 128, 256, 0, stream>>>(X, W, bias, Y);
    k_init <<<NBLK, 256, 0, stream>>>(deg, cnt, rowptr);
    k_hist <<<(NINC + 255) / 256, 256, 0, stream>>>(vertex, cnt);
    k_scan1<<<NBLK, 256, 0, stream>>>(cnt, bsum);
    k_scan2<<<1, 64, 0, stream>>>(bsum, boff);
    k_scan3<<<NBLK, 256, 0, stream>>>(cnt, boff, rowptr, fill);
    k_fill <<<(NINC + 255) / 256, 256, 0, stream>>>(vertex, fill, entries);
    k_edge <<<ME / 4, 256, 0, stream>>>(Y, vertex, deg, uvpos);
    k_xs   <<<(NV * 32) / 256, 256, 0, stream>>>(Y, deg, dinv);
    k_gather<<<NV / 4, 256, 0, stream>>>(Y, vertex, uvpos, rowptr, entries, dinv, out);
}

// Round 4
// 315.092 us; speedup vs baseline: 1.3271x; 1.3271x over previous
//
#include <hip/hip_runtime.h>
#include <hip/hip_bf16.h>

// Problem constants (HyperGCNConv: N=100000, M=50000, K=8, DIN=DOUT=128)
#define NV 100000
#define ME 50000
#define NINC (ME * 8)                     // 400000 incidences
#define NBLK ((NV + 255) / 256)           // 391 scan blocks
constexpr float WMED = 1.0f / 13.0f;      // 1/(2K-3), K=8

// ---------------- K1: Y = X @ W + b (fp32, vector ALU) ----------------
__global__ __launch_bounds__(256) void k_gemm(const float* __restrict__ X,
                                              const float* __restrict__ W,
                                              const float* __restrict__ bias,
                                              float* __restrict__ Y) {
    __shared__ float sX[128 * 68];
    __shared__ float sW[64 * 128];
    const int t = threadIdx.x;
    const int cg = t & 31;
    const int rg = t >> 5;
    const int row0 = blockIdx.x * 128;

    float acc[16][4];
    #pragma unroll
    for (int i = 0; i < 16; ++i) {
        acc[i][0] = 0.f; acc[i][1] = 0.f; acc[i][2] = 0.f; acc[i][3] = 0.f;
    }

    for (int h = 0; h < 2; ++h) {
        __syncthreads();
        #pragma unroll
        for (int i = 0; i < 8; ++i) {
            const int idx = t + i * 256;
            const int row = idx >> 4;
            const int kq  = idx & 15;
            int gr = row0 + row; if (gr > NV - 1) gr = NV - 1;
            const float4 v = *(const float4*)(X + (long)gr * 128 + h * 64 + kq * 4);
            *(float4*)(sX + row * 68 + kq * 4) = v;
        }
        #pragma unroll
        for (int i = 0; i < 8; ++i) {
            const int idx = t + i * 256;
            const int k  = idx >> 5;
            const int cq = idx & 31;
            const float4 v = *(const float4*)(W + (long)(h * 64 + k) * 128 + cq * 4);
            *(float4*)(sW + k * 128 + cq * 4) = v;
        }
        __syncthreads();

        #pragma unroll 4
        for (int k4 = 0; k4 < 16; ++k4) {
            const float4 w0 = *(const float4*)(sW + (k4 * 4 + 0) * 128 + cg * 4);
            const float4 w1 = *(const float4*)(sW + (k4 * 4 + 1) * 128 + cg * 4);
            const float4 w2 = *(const float4*)(sW + (k4 * 4 + 2) * 128 + cg * 4);
            const float4 w3 = *(const float4*)(sW + (k4 * 4 + 3) * 128 + cg * 4);
            #pragma unroll
            for (int i = 0; i < 16; ++i) {
                const float4 xq = *(const float4*)(sX + (rg * 16 + i) * 68 + k4 * 4);
                acc[i][0] = fmaf(xq.x, w0.x, acc[i][0]);
                acc[i][1] = fmaf(xq.x, w0.y, acc[i][1]);
                acc[i][2] = fmaf(xq.x, w0.z, acc[i][2]);
                acc[i][3] = fmaf(xq.x, w0.w, acc[i][3]);
                acc[i][0] = fmaf(xq.y, w1.x, acc[i][0]);
                acc[i][1] = fmaf(xq.y, w1.y, acc[i][1]);
                acc[i][2] = fmaf(xq.y, w1.z, acc[i][2]);
                acc[i][3] = fmaf(xq.y, w1.w, acc[i][3]);
                acc[i][0] = fmaf(xq.z, w2.x, acc[i][0]);
                acc[i][1] = fmaf(xq.z, w2.y, acc[i][1]);
                acc[i][2] = fmaf(xq.z, w2.z, acc[i][2]);
                acc[i][3] = fmaf(xq.z, w2.w, acc[i][3]);
                acc[i][0] = fmaf(xq.w, w3.x, acc[i][0]);
                acc[i][1] = fmaf(xq.w, w3.y, acc[i][1]);
                acc[i][2] = fmaf(xq.w, w3.z, acc[i][2]);
                acc[i][3] = fmaf(xq.w, w3.w, acc[i][3]);
            }
        }
    }

    const float4 bj = *(const float4*)(bias + cg * 4);
    #pragma unroll
    for (int i = 0; i < 16; ++i) {
        const int gr = row0 + rg * 16 + i;
        if (gr < NV) {
            float4 o;
            o.x = acc[i][0] + bj.x; o.y = acc[i][1] + bj.y;
            o.z = acc[i][2] + bj.z; o.w = acc[i][3] + bj.w;
            *(float4*)(Y + (long)gr * 128 + cg * 4) = o;
        }
    }
}

// ---------------- K2: per-hyperedge argmax pair (uvpos only) ----------------
__global__ __launch_bounds__(256) void k_edge(const float* __restrict__ Y,
                                              const int* __restrict__ vertex,
                                              int* __restrict__ uvpos) {
    __shared__ float sF[4][8 * 132];
    const int wid = threadIdx.x >> 6;
    const int lane = threadIdx.x & 63;
    const int m = blockIdx.x * 4 + wid;
    float* F = sF[wid];

    int verts[8];
    #pragma unroll
    for (int p = 0; p < 8; ++p) verts[p] = vertex[m * 8 + p];

    #pragma unroll
    for (int p = 0; p < 8; ++p) {
        const float2 v = *(const float2*)(Y + (long)verts[p] * 128 + lane * 2);
        *(float2*)(F + p * 132 + lane * 2) = v;
    }
    __syncthreads();

    const int k = lane >> 3, l = lane & 7;
    float acc = 0.0f;
    const float4* ra = (const float4*)(F + k * 132);
    const float4* rb = (const float4*)(F + l * 132);
    #pragma unroll
    for (int d4 = 0; d4 < 32; ++d4) {
        const float4 a = ra[d4], b = rb[d4];
        acc = fmaf(a.x, b.x, acc);
        acc = fmaf(a.y, b.y, acc);
        acc = fmaf(a.z, b.z, acc);
        acc = fmaf(a.w, b.w, acc);
    }
    const float sqk = __shfl(acc, k * 9);
    const float sql = __shfl(acc, l * 9);
    float v = sqk + sql - 2.0f * acc;
    int idx = lane;
    #pragma unroll
    for (int off = 32; off >= 1; off >>= 1) {
        const float ov = __shfl_xor(v, off);
        const int oi = __shfl_xor(idx, off);
        if (ov > v || (ov == v && oi < idx)) { v = ov; idx = oi; }
    }
    if (lane == 0) uvpos[m] = idx;
}

// ---------------- K2a: init cnt=0, rowptr[NV]=NINC ----------------
__global__ __launch_bounds__(256) void k_init(int* __restrict__ cnt,
                                              int* __restrict__ rowptr) {
    const int i = blockIdx.x * 256 + threadIdx.x;
    if (i < NV) cnt[i] = 0;
    if (i == 0) rowptr[NV] = NINC;
}

// ---------------- CSR build: histogram ----------------
__global__ __launch_bounds__(256) void k_hist(const int* __restrict__ vertex,
                                              int* __restrict__ cnt) {
    const int j = blockIdx.x * 256 + threadIdx.x;
    if (j < NINC) atomicAdd(cnt + vertex[j], 1);
}

// ---------------- CSR build: scan stage 1 (per-block sums) ----------------
__global__ __launch_bounds__(256) void k_scan1(const int* __restrict__ cnt,
                                               int* __restrict__ bsum) {
    __shared__ int s[256];
    const int t = threadIdx.x;
    const int i = blockIdx.x * 256 + t;
    s[t] = (i < NV) ? cnt[i] : 0;
    __syncthreads();
    #pragma unroll
    for (int off = 128; off >= 1; off >>= 1) {
        if (t < off) s[t] += s[t + off];
        __syncthreads();
    }
    if (t == 0) bsum[blockIdx.x] = s[0];
}

// ---------------- CSR build: scan stage 2 (exclusive scan of block sums) ---
__global__ __launch_bounds__(64) void k_scan2(const int* __restrict__ bsum,
                                              int* __restrict__ boff) {
    const int lane = threadIdx.x;   // single wave
    int running = 0;
    for (int c = 0; c * 64 < NBLK; ++c) {
        const int idx = c * 64 + lane;
        int v = (idx < NBLK) ? bsum[idx] : 0;
        int x = v;
        #pragma unroll
        for (int off = 1; off < 64; off <<= 1) {
            const int n = __shfl_up(x, off);
            if (lane >= off) x += n;
        }
        if (idx < NBLK) boff[idx] = running + x - v;   // exclusive
        running += __shfl(x, 63);
    }
}

// ---------------- CSR build: scan stage 3 (rowptr + fill ptr) ----------------
__global__ __launch_bounds__(256) void k_scan3(const int* __restrict__ cnt,
                                               const int* __restrict__ boff,
                                               int* __restrict__ rowptr,
                                               int* __restrict__ fill) {
    __shared__ int s[256];
    const int t = threadIdx.x;
    const int i = blockIdx.x * 256 + t;
    const int v = (i < NV) ? cnt[i] : 0;
    s[t] = v;
    __syncthreads();
    #pragma unroll
    for (int off = 1; off < 256; off <<= 1) {
        const int add = (t >= off) ? s[t - off] : 0;
        __syncthreads();
        s[t] += add;
        __syncthreads();
    }
    if (i < NV) {
        const int excl = boff[blockIdx.x] + s[t] - v;
        rowptr[i] = excl;
        fill[i] = excl;
    }
}

// ---------------- CSR build: fill entries with (m<<1)|role ----------------
// role 0 = u/v endpoint (reads w*S), role 1 = mediator (reads w*P)
__global__ __launch_bounds__(256) void k_fill(const int* __restrict__ vertex,
                                              const int* __restrict__ uvpos,
                                              int* __restrict__ fill,
                                              int* __restrict__ entries) {
    const int j = blockIdx.x * 256 + threadIdx.x;
    if (j < NINC) {
        const int v = vertex[j];
        const int m = j >> 3, p = j & 7;
        const int idx = uvpos[m];
        const int role = (p == (idx >> 3) || p == (idx & 7)) ? 0 : 1;
        const int slot = atomicAdd(fill + v, 1);
        entries[slot] = (m << 1) | role;
    }
}

// ---------------- K3: exact per-vertex degree (no atomics) ----------------
// deg_i = 1 + sum over incidences: 7w (endpoint role) or 2w (mediator role)
__global__ __launch_bounds__(256) void k_deg(const int* __restrict__ rowptr,
                                             const int* __restrict__ entries,
                                             float* __restrict__ deg) {
    const int i = blockIdx.x * 256 + threadIdx.x;
    if (i >= NV) return;
    const int start = rowptr[i], end = rowptr[i + 1];
    float d = 1.0f;
    for (int e = start; e < end; ++e)
        d += (entries[e] & 1) ? (2.0f * WMED) : (7.0f * WMED);
    deg[i] = d;
}

// ---------------- K4: per-edge w*S, w*P rows (bf16) ----------------
// S = sum_p dinv[v_p]*Y[v_p];  P = Xs[u]+Xs[v].  SP[2m]=w*S, SP[2m+1]=w*P.
__global__ __launch_bounds__(256) void k_sp(const float* __restrict__ Y,
                                            const int* __restrict__ vertex,
                                            const int* __restrict__ uvpos,
                                            const float* __restrict__ deg,
                                            __hip_bfloat16* __restrict__ SP) {
    const int wid = threadIdx.x >> 6;
    const int lane = threadIdx.x & 63;
    const int m = blockIdx.x * 4 + wid;
    const int d0 = lane, d1 = lane + 64;

    const int idx = uvpos[m];
    const int ui = idx >> 3, vi = idx & 7;

    float S0 = 0.f, S1 = 0.f, U0 = 0.f, U1 = 0.f, V0 = 0.f, V1 = 0.f;
    #pragma unroll
    for (int p = 0; p < 8; ++p) {
        const int vp = vertex[m * 8 + p];
        const float di = rsqrtf(deg[vp]);
        const float r0 = Y[(long)vp * 128 + d0] * di;
        const float r1 = Y[(long)vp * 128 + d1] * di;
        S0 += r0; S1 += r1;
        if (p == ui) { U0 = r0; U1 = r1; }
        if (p == vi) { V0 = r0; V1 = r1; }
    }
    __hip_bfloat16* Srow = SP + (long)(2 * m) * 128;
    __hip_bfloat16* Prow = Srow + 128;
    Srow[d0] = __float2bfloat16(WMED * S0);
    Srow[d1] = __float2bfloat16(WMED * S1);
    Prow[d0] = __float2bfloat16(WMED * (U0 + V0));
    Prow[d1] = __float2bfloat16(WMED * (U1 + V1));
}

// ---------------- K5: per-vertex gather: one bf16 row per incidence --------
// out_i = relu(dinv_i * ((1 - w*n_uv)*Xs_i + sum_e T[entries[e]]))
__global__ __launch_bounds__(256) void k_gather(const float* __restrict__ Y,
                                                const float* __restrict__ deg,
                                                const int* __restrict__ rowptr,
                                                const int* __restrict__ entries,
                                                const __hip_bfloat16* __restrict__ SP,
                                                float* __restrict__ out) {
    const int wid = threadIdx.x >> 6;
    const int lane = threadIdx.x & 63;
    const int i = blockIdx.x * 4 + wid;
    const int d0 = lane, d1 = lane + 64;

    const float din = rsqrtf(deg[i]);
    const float xs0 = Y[(long)i * 128 + d0] * din;
    const float xs1 = Y[(long)i * 128 + d1] * din;

    float a0 = 0.f, a1 = 0.f;
    int nuv = 0;
    const int start = rowptr[i], end = rowptr[i + 1];
    for (int e = start; e < end; ++e) {
        const int t = entries[e];
        nuv += (t & 1) ^ 1;
        const __hip_bfloat16* T = SP + (long)t * 128;
        a0 += __bfloat162float(T[d0]);
        a1 += __bfloat162float(T[d1]);
    }
    const float self = 1.0f - WMED * (float)nuv;
    a0 = fmaf(self, xs0, a0);
    a1 = fmaf(self, xs1, a1);
    out[(long)i * 128 + d0] = fmaxf(a0 * din, 0.0f);
    out[(long)i * 128 + d1] = fmaxf(a1 * din, 0.0f);
}

extern "C" void kernel_launch(void* const* d_in, const int* in_sizes, int n_in,
                              void* d_out, int out_size, void* d_ws, size_t ws_size,
                              hipStream_t stream) {
    const float* X      = (const float*)d_in[0];   // [N,128]
    const int*   vertex = (const int*)d_in[1];     // [M*8]
    // d_in[2] = edges (repeat(arange(M),8)) -- unused
    const float* W      = (const float*)d_in[3];   // [128,128]
    const float* bias   = (const float*)d_in[4];   // [128]
    float* out = (float*)d_out;                    // [N,128]

    // workspace: Y[N*128] f32 | SP[2M*128] bf16 | deg[N] | uvpos[M] | cnt[N] |
    //            rowptr[N+1] | fill[N] | bsum[NBLK] | boff[NBLK] | entries[NINC]
    float* Y              = (float*)d_ws;
    __hip_bfloat16* SP    = (__hip_bfloat16*)(Y + (long)NV * 128);
    float* deg            = (float*)(SP + (long)2 * ME * 128);
    int*   uvpos          = (int*)(deg + NV);
    int*   cnt            = uvpos + ME;
    int*   rowptr         = cnt + NV;
    int*   fill           = rowptr + NV + 1;
    int*   bsum           = fill + NV;
    int*   boff           = bsum + NBLK;
    int*   entries        = boff + NBLK;

    k_gemm <<<(NV + 127) / 128, 256, 0, stream>>>(X, W, bias, Y);
    k_edge <<<ME / 4, 256, 0, stream>>>(Y, vertex, uvpos);
    k_init <<<NBLK, 256, 0, stream>>>(cnt, rowptr);
    k_hist <<<(NINC + 255) / 256, 256, 0, stream>>>(vertex, cnt);
    k_scan1<<<NBLK, 256, 0, stream>>>(cnt, bsum);
    k_scan2<<<1, 64, 0, stream>>>(bsum, boff);
    k_scan3<<<NBLK, 256, 0, stream>>>(cnt, boff, rowptr, fill);
    k_fill <<<(NINC + 255) / 256, 256, 0, stream>>>(vertex, uvpos, fill, entries);
    k_deg  <<<NBLK, 256, 0, stream>>>(rowptr, entries, deg);
    k_sp   <<<ME / 4, 256, 0, stream>>>(Y, vertex, uvpos, deg, SP);
    k_gather<<<NV / 4, 256, 0, stream>>>(Y, deg, rowptr, entries, SP, out);
}